// Round 5
// baseline (321.886 us; speedup 1.0000x reference)
//
#include <hip/hip_runtime.h>
#include <cstddef>

// ---------------------------------------------------------------------------
// B=2, N=2048, C=1024, H=16, Dh=64, scale = Dh//H = 4
// qkv: mixed-precision MFMA GEMM, one launch:
//      q,k cols (n0<2048): bf16x3 split -> fp32 [B,H,N,64]
//      v  cols (n0>=2048): bf16x1      -> bf16 [B,H,N,64]
// attn: banded softmax (masked logits = 1e-9 folded analytically), fp32 q/k,
//       bf16 v, LDS-free / barrier-free, 8 lanes per query row.
// proj: [4096x1024] x [1024x1024]^T + bias -> out fp32  (bf16 MFMA)
// ---------------------------------------------------------------------------

typedef short  bf16x8 __attribute__((ext_vector_type(8)));
typedef float  f32x4  __attribute__((ext_vector_type(4)));

__device__ __forceinline__ void gl_lds16(const void* g, void* l) {
    __builtin_amdgcn_global_load_lds(
        (const __attribute__((address_space(1))) void*)g,
        (__attribute__((address_space(3))) void*)l, 16, 0, 0);
}

__device__ __forceinline__ ushort f2bf_rne(float f) {
    unsigned b = __float_as_uint(f);
    b += 0x7FFFu + ((b >> 16) & 1u);
    return (ushort)(b >> 16);
}
__device__ __forceinline__ float bf2f_lo(unsigned u) { return __uint_as_float(u << 16); }
__device__ __forceinline__ float bf2f_hi(unsigned u) { return __uint_as_float(u & 0xffff0000u); }

// ---------------------------------------------------------------------------
// fused fp32 -> bf16 split for all three tensors in one launch.
// ---------------------------------------------------------------------------
__global__ void split_all(const float* __restrict__ x,
                          const float* __restrict__ qkvw,
                          const float* __restrict__ projw,
                          ushort* __restrict__ xh, ushort* __restrict__ xl,
                          ushort* __restrict__ wh, ushort* __restrict__ wl,
                          ushort* __restrict__ pwh)
{
    const int i = blockIdx.x * 256 + threadIdx.x;
    const float* src; ushort* hi; ushort* lo; int j;
    if (i < 1048576)      { src = x;     hi = xh;  lo = xl;     j = i; }
    else if (i < 1835008) { src = qkvw;  hi = wh;  lo = wl;     j = i - 1048576; }
    else                  { src = projw; hi = pwh; lo = nullptr; j = i - 1835008; }

    float4 v = ((const float4*)src)[j];
    ushort h0 = f2bf_rne(v.x), h1 = f2bf_rne(v.y), h2 = f2bf_rne(v.z), h3 = f2bf_rne(v.w);
    ((ushort4*)hi)[j] = make_ushort4(h0, h1, h2, h3);
    if (lo) {
        float r0 = v.x - __uint_as_float((unsigned)h0 << 16);
        float r1 = v.y - __uint_as_float((unsigned)h1 << 16);
        float r2 = v.z - __uint_as_float((unsigned)h2 << 16);
        float r3 = v.w - __uint_as_float((unsigned)h3 << 16);
        ((ushort4*)lo)[j] = make_ushort4(f2bf_rne(r0), f2bf_rne(r1), f2bf_rne(r2), f2bf_rne(r3));
    }
}

// ---------------------------------------------------------------------------
// Mixed qkv GEMM: 128x128 tile, BK=32, 4 waves x (4x4) 16x16x32 bf16 tiles.
// q,k blocks: 3-term split, fp32 scatter. v blocks: 1-term, bf16 scatter.
// ---------------------------------------------------------------------------
__global__ __launch_bounds__(256) void gemm_qkv(
    const ushort* __restrict__ Ah_g, const ushort* __restrict__ Al_g,
    const ushort* __restrict__ Wh_g, const ushort* __restrict__ Wl_g,
    float* __restrict__ qk_out, ushort* __restrict__ v_out)
{
    const int K = 1024;
    __shared__ ushort smem[16384];
    ushort* AhS = smem;
    ushort* AlS = smem + 4096;
    ushort* WhS = smem + 8192;
    ushort* WlS = smem + 12288;

    const int tid  = threadIdx.x;
    const int wid  = tid >> 6;
    const int lane = tid & 63;
    const int quad = lane >> 4;
    const int cl   = lane & 15;
    const int m0 = blockIdx.y * 128;
    const int n0 = blockIdx.x * 128;
    const bool three = (n0 < 2048);        // q,k need the split; v doesn't
    const int wm = (wid & 1) * 64;
    const int wn = (wid >> 1) * 64;
    const int srow = lane >> 2;
    const int scol = (lane & 3) * 8;

    const ushort* src; ushort* dst; int r0, c0, cn;
    if (three) {
        src = (wid == 0) ? Ah_g : (wid == 1) ? Al_g : (wid == 2) ? Wh_g : Wl_g;
        dst = (wid == 0) ? AhS : (wid == 1) ? AlS : (wid == 2) ? WhS : WlS;
        r0 = (wid < 2) ? m0 : n0; c0 = 0; cn = 8;
    } else {
        src = (wid < 2) ? Ah_g : Wh_g;
        dst = (wid < 2) ? AhS : WhS;
        r0 = (wid < 2) ? m0 : n0; c0 = (wid & 1) * 4; cn = 4;
    }

    f32x4 acc[4][4];
#pragma unroll
    for (int i = 0; i < 4; ++i)
#pragma unroll
        for (int j = 0; j < 4; ++j) acc[i][j] = (f32x4){0.f, 0.f, 0.f, 0.f};

    for (int k0 = 0; k0 < K; k0 += 32) {
        for (int c = 0; c < cn; ++c) {
            const int cc = c0 + c;
            gl_lds16(src + (size_t)(r0 + cc * 16 + srow) * K + k0 + scol, dst + cc * 512);
        }
        __syncthreads();

        bf16x8 ah[4], wh[4];
#pragma unroll
        for (int i = 0; i < 4; ++i) {
            ah[i] = ((const bf16x8*)AhS)[(wm + i * 16 + cl) * 4 + quad];
            wh[i] = ((const bf16x8*)WhS)[(wn + i * 16 + cl) * 4 + quad];
        }
        if (three) {
            bf16x8 al[4], wl[4];
#pragma unroll
            for (int i = 0; i < 4; ++i) {
                al[i] = ((const bf16x8*)AlS)[(wm + i * 16 + cl) * 4 + quad];
                wl[i] = ((const bf16x8*)WlS)[(wn + i * 16 + cl) * 4 + quad];
            }
#pragma unroll
            for (int mi = 0; mi < 4; ++mi)
#pragma unroll
                for (int ni = 0; ni < 4; ++ni) {
                    acc[mi][ni] = __builtin_amdgcn_mfma_f32_16x16x32_bf16(ah[mi], wh[ni], acc[mi][ni], 0, 0, 0);
                    acc[mi][ni] = __builtin_amdgcn_mfma_f32_16x16x32_bf16(ah[mi], wl[ni], acc[mi][ni], 0, 0, 0);
                    acc[mi][ni] = __builtin_amdgcn_mfma_f32_16x16x32_bf16(al[mi], wh[ni], acc[mi][ni], 0, 0, 0);
                }
        } else {
#pragma unroll
            for (int mi = 0; mi < 4; ++mi)
#pragma unroll
                for (int ni = 0; ni < 4; ++ni)
                    acc[mi][ni] = __builtin_amdgcn_mfma_f32_16x16x32_bf16(ah[mi], wh[ni], acc[mi][ni], 0, 0, 0);
        }
        __syncthreads();
    }

#pragma unroll
    for (int mi = 0; mi < 4; ++mi)
#pragma unroll
        for (int r = 0; r < 4; ++r) {
            const int gm = m0 + wm + mi * 16 + quad * 4 + r;
            const int b  = gm >> 11;
            const int nn = gm & 2047;
#pragma unroll
            for (int ni = 0; ni < 4; ++ni) {
                const int gn = n0 + wn + ni * 16 + cl;
                const int h  = (gn >> 6) & 15;
                const int dh = gn & 63;
                const size_t idx = (((size_t)b * 16 + h) * 2048 + nn) * 64 + dh;
                if (three) {
                    const int s = gn >> 10;           // 0:q 1:k
                    qk_out[(size_t)s * 4194304u + idx] = acc[mi][ni][r];
                } else {
                    v_out[idx] = f2bf_rne(acc[mi][ni][r]);
                }
            }
        }
}

// S_all[bh][d] = sum_n v[bh][n][d] from bf16 v. 32 blocks x 256 thr, LDS reduce.
__global__ void sall_sum(const ushort* __restrict__ vg16, float* __restrict__ sall)
{
    __shared__ float red[4][64];
    const int bh = blockIdx.x;
    const int tid = threadIdx.x;
    const int d = tid & 63;
    const int c = tid >> 6;
    const ushort* base = vg16 + (((size_t)bh * 2048) + (size_t)c * 512) * 64 + d;
    float s = 0.f;
#pragma unroll 8
    for (int nn = 0; nn < 512; ++nn)
        s += bf2f_lo((unsigned)base[(size_t)nn * 64]);
    red[c][d] = s;
    __syncthreads();
    if (tid < 64)
        sall[bh * 64 + tid] = red[0][tid] + red[1][tid] + red[2][tid] + red[3][tid];
}

// ---------------------------------------------------------------------------
// Banded attention, LDS-free & barrier-free. 8 lanes own one query row
// (lane p = lane&7 owns dims [p*8, p*8+8)). K fp32, V bf16 from global.
// ---------------------------------------------------------------------------
__global__ __launch_bounds__(256) void attn_band(
    const float* __restrict__ qg,
    const float* __restrict__ kg,
    const ushort* __restrict__ vg16,
    const float* __restrict__ sall,
    ushort* __restrict__ outp,
    const int* __restrict__ epoch_ptr)
{
    const int N = 2048;
    const int w = (epoch_ptr[0] < 15) ? 16 : 20;

    const int tid  = threadIdx.x;
    const int wid  = tid >> 6;
    const int lane = tid & 63;
    const int p    = lane & 7;
    const int rg   = lane >> 3;

    const int bh = blockIdx.x >> 6;
    const int n  = ((blockIdx.x & 63) << 5) + wid * 8 + rg;

    const int jlo = max(0, n - w);
    const int jhi = min(N - 1, n + w);
    const int bc  = jhi - jlo + 1;      // <= 41

    const float* qp = qg + ((size_t)bh * N + n) * 64 + p * 8;
    const float4 q0 = ((const float4*)qp)[0];
    const float4 q1 = ((const float4*)qp)[1];

    // Phase B: logits from global K
    const float* kbase = kg + ((size_t)bh * N + jlo) * 64 + p * 8;
    float lg[44];
#pragma unroll
    for (int i = 0; i < 44; ++i) {
        if (i < bc) {
            const float4* kp = (const float4*)(kbase + (size_t)i * 64);
            float4 k0 = kp[0], k1 = kp[1];
            float t = q0.x*k0.x + q0.y*k0.y + q0.z*k0.z + q0.w*k0.w
                    + q1.x*k1.x + q1.y*k1.y + q1.z*k1.z + q1.w*k1.w;
            t += __shfl_xor(t, 1);
            t += __shfl_xor(t, 2);
            t += __shfl_xor(t, 4);
            lg[i] = 4.0f * t;
        }
    }

    // Phase C: exact full-row softmax (masked logits = 1e-9, count N-bc)
    float m = 1e-9f;
#pragma unroll
    for (int i = 0; i < 44; ++i)
        if (i < bc) m = fmaxf(m, lg[i]);
    const float em = __expf(1e-9f - m);
    float denom = (float)(N - bc) * em;
#pragma unroll
    for (int i = 0; i < 44; ++i)
        if (i < bc) { float e = __expf(lg[i] - m); lg[i] = e; denom += e; }
    const float inv = 1.0f / denom;
    const float pm = em * inv;
#pragma unroll
    for (int i = 0; i < 44; ++i)
        if (i < bc) lg[i] = (lg[i] - em) * inv;

    // Phase D: weighted bf16-V accumulation (16B per lane per offset)
    float acc[8];
#pragma unroll
    for (int d = 0; d < 8; ++d) acc[d] = 0.f;
    const ushort* vbase = vg16 + ((size_t)bh * N + jlo) * 64 + p * 8;
#pragma unroll
    for (int i = 0; i < 44; ++i) {
        if (i < bc) {
            const float s = lg[i];
            uint4 vv = *(const uint4*)(vbase + (size_t)i * 64);
            acc[0] += s * bf2f_lo(vv.x); acc[1] += s * bf2f_hi(vv.x);
            acc[2] += s * bf2f_lo(vv.y); acc[3] += s * bf2f_hi(vv.y);
            acc[4] += s * bf2f_lo(vv.z); acc[5] += s * bf2f_hi(vv.z);
            acc[6] += s * bf2f_lo(vv.w); acc[7] += s * bf2f_hi(vv.w);
        }
    }

    const int b = bh >> 4;
    const int h = bh & 15;
    const float* sp = sall + bh * 64 + p * 8;
    float4 s0 = ((const float4*)sp)[0], s1 = ((const float4*)sp)[1];
    float o[8];
    o[0] = acc[0] + pm * s0.x; o[1] = acc[1] + pm * s0.y;
    o[2] = acc[2] + pm * s0.z; o[3] = acc[3] + pm * s0.w;
    o[4] = acc[4] + pm * s1.x; o[5] = acc[5] + pm * s1.y;
    o[6] = acc[6] + pm * s1.z; o[7] = acc[7] + pm * s1.w;

    unsigned u[4];
#pragma unroll
    for (int j = 0; j < 4; ++j)
        u[j] = (unsigned)f2bf_rne(o[2 * j]) | ((unsigned)f2bf_rne(o[2 * j + 1]) << 16);
    uint4* dstv = (uint4*)(outp + (((size_t)b * N + n) * 1024) + h * 64 + p * 8);
    dstv[0] = make_uint4(u[0], u[1], u[2], u[3]);
}

// ---------------------------------------------------------------------------
// Proj GEMM: 1-term bf16 MFMA, fp32 out + bias (m97 structure).
// ---------------------------------------------------------------------------
__global__ __launch_bounds__(256) void gemm_proj(
    const ushort* __restrict__ Ah_g, const ushort* __restrict__ Wh_g,
    const float* __restrict__ bias, float* __restrict__ out)
{
    const int K = 1024, Nout = 1024;
    __shared__ ushort smem[8192];
    ushort* AhS = smem;
    ushort* WhS = smem + 4096;

    const int tid  = threadIdx.x;
    const int wid  = tid >> 6;
    const int lane = tid & 63;
    const int quad = lane >> 4;
    const int cl   = lane & 15;
    const int m0 = blockIdx.y * 128;
    const int n0 = blockIdx.x * 128;
    const int wm = (wid & 1) * 64;
    const int wn = (wid >> 1) * 64;
    const int srow = lane >> 2;
    const int scol = (lane & 3) * 8;

    const ushort* src = (wid < 2) ? Ah_g : Wh_g;
    ushort* dst = (wid < 2) ? AhS : WhS;
    const int r0 = (wid < 2) ? m0 : n0;
    const int c0 = (wid & 1) * 4;

    f32x4 acc[4][4];
#pragma unroll
    for (int i = 0; i < 4; ++i)
#pragma unroll
        for (int j = 0; j < 4; ++j) acc[i][j] = (f32x4){0.f, 0.f, 0.f, 0.f};

    for (int k0 = 0; k0 < K; k0 += 32) {
#pragma unroll
        for (int c = 0; c < 4; ++c) {
            const int cc = c0 + c;
            gl_lds16(src + (size_t)(r0 + cc * 16 + srow) * K + k0 + scol, dst + cc * 512);
        }
        __syncthreads();
        bf16x8 ah[4], wh[4];
#pragma unroll
        for (int i = 0; i < 4; ++i) {
            ah[i] = ((const bf16x8*)AhS)[(wm + i * 16 + cl) * 4 + quad];
            wh[i] = ((const bf16x8*)WhS)[(wn + i * 16 + cl) * 4 + quad];
        }
#pragma unroll
        for (int mi = 0; mi < 4; ++mi)
#pragma unroll
            for (int ni = 0; ni < 4; ++ni)
                acc[mi][ni] = __builtin_amdgcn_mfma_f32_16x16x32_bf16(ah[mi], wh[ni], acc[mi][ni], 0, 0, 0);
        __syncthreads();
    }

    float bb[4];
#pragma unroll
    for (int ni = 0; ni < 4; ++ni) bb[ni] = bias[n0 + wn + ni * 16 + cl];
#pragma unroll
    for (int mi = 0; mi < 4; ++mi)
#pragma unroll
        for (int r = 0; r < 4; ++r) {
            const int gm = m0 + wm + mi * 16 + quad * 4 + r;
            float* rowp = out + (size_t)gm * Nout;
#pragma unroll
            for (int ni = 0; ni < 4; ++ni) {
                const int gn = n0 + wn + ni * 16 + cl;
                rowp[gn] = acc[mi][ni][r] + bb[ni];
            }
        }
}

extern "C" void kernel_launch(void* const* d_in, const int* in_sizes, int n_in,
                              void* d_out, int out_size, void* d_ws, size_t ws_size,
                              hipStream_t stream)
{
    const float* x      = (const float*)d_in[0];
    const float* qkv_w  = (const float*)d_in[1];
    const float* proj_w = (const float*)d_in[2];
    const float* proj_b = (const float*)d_in[3];
    const int*   epoch  = (const int*)d_in[4];
    float* out = (float*)d_out;

    const size_t BHND = (size_t)2 * 16 * 2048 * 64;   // 4,194,304
    const size_t XN = 4194304, WN = 3145728;

    float*  qw   = (float*)d_ws;          // q fp32
    float*  kw   = qw + BHND;             // k fp32
    float*  sall = kw + BHND;             // 2048 used
    ushort* vw16 = (ushort*)(sall + 4096);// v bf16
    ushort* xh   = vw16 + BHND;
    ushort* xl   = xh + XN;
    ushort* wh   = xl + XN;
    ushort* wl   = wh + WN;
    ushort* pwh  = wl + WN;
    ushort* ao   = xh;   // alias: xh/xl dead after qkv gemm

    split_all<<<dim3(8192), dim3(256), 0, stream>>>(
        x, qkv_w, proj_w, xh, xl, wh, wl, pwh);

    gemm_qkv<<<dim3(24, 32), dim3(256), 0, stream>>>(
        xh, xl, wh, wl, qw, vw16);

    sall_sum<<<dim3(32), dim3(256), 0, stream>>>(vw16, sall);

    attn_band<<<dim3(2048), dim3(256), 0, stream>>>(qw, kw, vw16, sall, ao, epoch);

    gemm_proj<<<dim3(8, 32), dim3(256), 0, stream>>>(ao, pwh, proj_b, out);
}

// Round 6
// 276.250 us; speedup vs baseline: 1.1652x; 1.1652x over previous
//
#include <hip/hip_runtime.h>
#include <cstddef>

// ---------------------------------------------------------------------------
// B=2, N=2048, C=1024, H=16, Dh=64, scale = Dh//H = 4
// qkv in two UNIFORM launches (round-5 mixed kernel blew VGPR/occupancy):
//   gemm_mfma<3,0>: q,k cols, bf16x3 split -> fp32 q|k [B,H,N,64]
//   gemm_mfma<1,2>: v  cols, bf16x1       -> bf16 v    [B,H,N,64]
// attn: banded softmax (masked logits = 1e-9 folded analytically), fp32 q/k,
//       bf16 v, LDS-free / barrier-free, 8 lanes per query row.
// proj: gemm_mfma<1,1>: [4096x1024] x [1024x1024]^T + bias -> fp32 out
// ---------------------------------------------------------------------------

typedef short  bf16x8 __attribute__((ext_vector_type(8)));
typedef float  f32x4  __attribute__((ext_vector_type(4)));

__device__ __forceinline__ void gl_lds16(const void* g, void* l) {
    __builtin_amdgcn_global_load_lds(
        (const __attribute__((address_space(1))) void*)g,
        (__attribute__((address_space(3))) void*)l, 16, 0, 0);
}

__device__ __forceinline__ ushort f2bf_rne(float f) {
    unsigned b = __float_as_uint(f);
    b += 0x7FFFu + ((b >> 16) & 1u);
    return (ushort)(b >> 16);
}
__device__ __forceinline__ float bf2f_lo(unsigned u) { return __uint_as_float(u << 16); }
__device__ __forceinline__ float bf2f_hi(unsigned u) { return __uint_as_float(u & 0xffff0000u); }

// ---------------------------------------------------------------------------
// fused fp32 -> bf16 split for all three tensors in one launch.
// ---------------------------------------------------------------------------
__global__ void split_all(const float* __restrict__ x,
                          const float* __restrict__ qkvw,
                          const float* __restrict__ projw,
                          ushort* __restrict__ xh, ushort* __restrict__ xl,
                          ushort* __restrict__ wh, ushort* __restrict__ wl,
                          ushort* __restrict__ pwh)
{
    const int i = blockIdx.x * 256 + threadIdx.x;
    const float* src; ushort* hi; ushort* lo; int j;
    if (i < 1048576)      { src = x;     hi = xh;  lo = xl;     j = i; }
    else if (i < 1835008) { src = qkvw;  hi = wh;  lo = wl;     j = i - 1048576; }
    else                  { src = projw; hi = pwh; lo = nullptr; j = i - 1835008; }

    float4 v = ((const float4*)src)[j];
    ushort h0 = f2bf_rne(v.x), h1 = f2bf_rne(v.y), h2 = f2bf_rne(v.z), h3 = f2bf_rne(v.w);
    ((ushort4*)hi)[j] = make_ushort4(h0, h1, h2, h3);
    if (lo) {
        float r0 = v.x - __uint_as_float((unsigned)h0 << 16);
        float r1 = v.y - __uint_as_float((unsigned)h1 << 16);
        float r2 = v.z - __uint_as_float((unsigned)h2 << 16);
        float r3 = v.w - __uint_as_float((unsigned)h3 << 16);
        ((ushort4*)lo)[j] = make_ushort4(f2bf_rne(r0), f2bf_rne(r1), f2bf_rne(r2), f2bf_rne(r3));
    }
}

// ---------------------------------------------------------------------------
// MFMA GEMM (m97 structure): 128x128 tile, BK=32, 4 waves x (4x4) 16x16x32.
// NTERMS=3: acc += Ah*Wh + Ah*Wl + Al*Wh.
// EPI=0: scatter fp32 into q|k [B,H,N,64]  (expects n0 < 2048 columns)
// EPI=1: out = acc + bias, fp32 row-major
// EPI=2: scatter bf16 into v [B,H,N,64]    (W pointer pre-offset to v cols)
// ---------------------------------------------------------------------------
template <int NTERMS, int EPI>
__global__ __launch_bounds__(256) void gemm_mfma(
    const ushort* __restrict__ Ah_g, const ushort* __restrict__ Al_g,
    const ushort* __restrict__ Wh_g, const ushort* __restrict__ Wl_g,
    const float* __restrict__ bias,
    float* __restrict__ out, ushort* __restrict__ out16,
    int K, int Nout)
{
    __shared__ ushort smem[(NTERMS == 3 ? 4 : 2) * 4096];
    ushort* AhS = smem;
    ushort* AlS = (NTERMS == 3) ? smem + 4096 : nullptr;
    ushort* WhS = (NTERMS == 3) ? smem + 8192 : smem + 4096;
    ushort* WlS = (NTERMS == 3) ? smem + 12288 : nullptr;

    const int tid  = threadIdx.x;
    const int wid  = tid >> 6;
    const int lane = tid & 63;
    const int quad = lane >> 4;
    const int cl   = lane & 15;
    const int m0 = blockIdx.y * 128;
    const int n0 = blockIdx.x * 128;
    const int wm = (wid & 1) * 64;
    const int wn = (wid >> 1) * 64;

    const int srow = lane >> 2;
    const int scol = (lane & 3) * 8;

    const ushort* src; ushort* dst; int r0, c0, cn;
    if (NTERMS == 3) {
        src = (wid == 0) ? Ah_g : (wid == 1) ? Al_g : (wid == 2) ? Wh_g : Wl_g;
        dst = (wid == 0) ? AhS : (wid == 1) ? AlS : (wid == 2) ? WhS : WlS;
        r0 = (wid < 2) ? m0 : n0;
        c0 = 0; cn = 8;
    } else {
        src = (wid < 2) ? Ah_g : Wh_g;
        dst = (wid < 2) ? AhS : WhS;
        r0 = (wid < 2) ? m0 : n0;
        c0 = (wid & 1) * 4; cn = 4;
    }

    f32x4 acc[4][4];
#pragma unroll
    for (int i = 0; i < 4; ++i)
#pragma unroll
        for (int j = 0; j < 4; ++j) acc[i][j] = (f32x4){0.f, 0.f, 0.f, 0.f};

    for (int k0 = 0; k0 < K; k0 += 32) {
#pragma unroll
        for (int c = 0; c < ((NTERMS == 3) ? 8 : 4); ++c) {
            const int cc = c0 + (NTERMS == 3 ? c : (c & 3));
            if (NTERMS != 3 && c >= cn) break;
            const ushort* g = src + (size_t)(r0 + cc * 16 + srow) * K + k0 + scol;
            gl_lds16(g, dst + cc * 512);
        }
        __syncthreads();

        bf16x8 ah[4], wh[4];
#pragma unroll
        for (int i = 0; i < 4; ++i) {
            ah[i] = ((const bf16x8*)AhS)[(wm + i * 16 + cl) * 4 + quad];
            wh[i] = ((const bf16x8*)WhS)[(wn + i * 16 + cl) * 4 + quad];
        }
        if (NTERMS == 3) {
            bf16x8 al[4], wl[4];
#pragma unroll
            for (int i = 0; i < 4; ++i) {
                al[i] = ((const bf16x8*)AlS)[(wm + i * 16 + cl) * 4 + quad];
                wl[i] = ((const bf16x8*)WlS)[(wn + i * 16 + cl) * 4 + quad];
            }
#pragma unroll
            for (int mi = 0; mi < 4; ++mi)
#pragma unroll
                for (int ni = 0; ni < 4; ++ni) {
                    acc[mi][ni] = __builtin_amdgcn_mfma_f32_16x16x32_bf16(ah[mi], wh[ni], acc[mi][ni], 0, 0, 0);
                    acc[mi][ni] = __builtin_amdgcn_mfma_f32_16x16x32_bf16(ah[mi], wl[ni], acc[mi][ni], 0, 0, 0);
                    acc[mi][ni] = __builtin_amdgcn_mfma_f32_16x16x32_bf16(al[mi], wh[ni], acc[mi][ni], 0, 0, 0);
                }
        } else {
#pragma unroll
            for (int mi = 0; mi < 4; ++mi)
#pragma unroll
                for (int ni = 0; ni < 4; ++ni)
                    acc[mi][ni] = __builtin_amdgcn_mfma_f32_16x16x32_bf16(ah[mi], wh[ni], acc[mi][ni], 0, 0, 0);
        }
        __syncthreads();
    }

    if (EPI == 1) {
        float bb[4];
#pragma unroll
        for (int ni = 0; ni < 4; ++ni) bb[ni] = bias[n0 + wn + ni * 16 + cl];
#pragma unroll
        for (int mi = 0; mi < 4; ++mi)
#pragma unroll
            for (int r = 0; r < 4; ++r) {
                const int gm = m0 + wm + mi * 16 + quad * 4 + r;
                float* rowp = out + (size_t)gm * Nout;
#pragma unroll
                for (int ni = 0; ni < 4; ++ni) {
                    const int gn = n0 + wn + ni * 16 + cl;
                    rowp[gn] = acc[mi][ni][r] + bb[ni];
                }
            }
    } else {
#pragma unroll
        for (int mi = 0; mi < 4; ++mi)
#pragma unroll
            for (int r = 0; r < 4; ++r) {
                const int gm = m0 + wm + mi * 16 + quad * 4 + r;
                const int b  = gm >> 11;
                const int nn = gm & 2047;
#pragma unroll
                for (int ni = 0; ni < 4; ++ni) {
                    const int gn = n0 + wn + ni * 16 + cl;
                    const int h  = (gn >> 6) & 15;
                    const int dh = gn & 63;
                    const size_t idx = (((size_t)b * 16 + h) * 2048 + nn) * 64 + dh;
                    if (EPI == 0) {
                        const int s = gn >> 10;     // 0:q 1:k (n0 < 2048)
                        out[(size_t)s * 4194304u + idx] = acc[mi][ni][r];
                    } else {                        // EPI == 2: v bf16
                        out16[idx] = f2bf_rne(acc[mi][ni][r]);
                    }
                }
            }
    }
}

// S_all[bh][d] = sum_n v[bh][n][d] from bf16 v. 32 blocks x 256 thr, LDS reduce.
__global__ void sall_sum(const ushort* __restrict__ vg16, float* __restrict__ sall)
{
    __shared__ float red[4][64];
    const int bh = blockIdx.x;
    const int tid = threadIdx.x;
    const int d = tid & 63;
    const int c = tid >> 6;
    const ushort* base = vg16 + (((size_t)bh * 2048) + (size_t)c * 512) * 64 + d;
    float s = 0.f;
#pragma unroll 8
    for (int nn = 0; nn < 512; ++nn)
        s += bf2f_lo((unsigned)base[(size_t)nn * 64]);
    red[c][d] = s;
    __syncthreads();
    if (tid < 64)
        sall[bh * 64 + tid] = red[0][tid] + red[1][tid] + red[2][tid] + red[3][tid];
}

// ---------------------------------------------------------------------------
// Banded attention, LDS-free & barrier-free. 8 lanes own one query row
// (lane p = lane&7 owns dims [p*8, p*8+8)). K fp32, V bf16 from global.
// ---------------------------------------------------------------------------
__global__ __launch_bounds__(256) void attn_band(
    const float* __restrict__ qg,
    const float* __restrict__ kg,
    const ushort* __restrict__ vg16,
    const float* __restrict__ sall,
    ushort* __restrict__ outp,
    const int* __restrict__ epoch_ptr)
{
    const int N = 2048;
    const int w = (epoch_ptr[0] < 15) ? 16 : 20;

    const int tid  = threadIdx.x;
    const int wid  = tid >> 6;
    const int lane = tid & 63;
    const int p    = lane & 7;
    const int rg   = lane >> 3;

    const int bh = blockIdx.x >> 6;
    const int n  = ((blockIdx.x & 63) << 5) + wid * 8 + rg;

    const int jlo = max(0, n - w);
    const int jhi = min(N - 1, n + w);
    const int bc  = jhi - jlo + 1;      // <= 41

    const float* qp = qg + ((size_t)bh * N + n) * 64 + p * 8;
    const float4 q0 = ((const float4*)qp)[0];
    const float4 q1 = ((const float4*)qp)[1];

    // Phase B: logits from global K
    const float* kbase = kg + ((size_t)bh * N + jlo) * 64 + p * 8;
    float lg[44];
#pragma unroll
    for (int i = 0; i < 44; ++i) {
        if (i < bc) {
            const float4* kp = (const float4*)(kbase + (size_t)i * 64);
            float4 k0 = kp[0], k1 = kp[1];
            float t = q0.x*k0.x + q0.y*k0.y + q0.z*k0.z + q0.w*k0.w
                    + q1.x*k1.x + q1.y*k1.y + q1.z*k1.z + q1.w*k1.w;
            t += __shfl_xor(t, 1);
            t += __shfl_xor(t, 2);
            t += __shfl_xor(t, 4);
            lg[i] = 4.0f * t;
        }
    }

    // Phase C: exact full-row softmax (masked logits = 1e-9, count N-bc)
    float m = 1e-9f;
#pragma unroll
    for (int i = 0; i < 44; ++i)
        if (i < bc) m = fmaxf(m, lg[i]);
    const float em = __expf(1e-9f - m);
    float denom = (float)(N - bc) * em;
#pragma unroll
    for (int i = 0; i < 44; ++i)
        if (i < bc) { float e = __expf(lg[i] - m); lg[i] = e; denom += e; }
    const float inv = 1.0f / denom;
    const float pm = em * inv;
#pragma unroll
    for (int i = 0; i < 44; ++i)
        if (i < bc) lg[i] = (lg[i] - em) * inv;

    // Phase D: weighted bf16-V accumulation (16B per lane per offset)
    float acc[8];
#pragma unroll
    for (int d = 0; d < 8; ++d) acc[d] = 0.f;
    const ushort* vbase = vg16 + ((size_t)bh * N + jlo) * 64 + p * 8;
#pragma unroll
    for (int i = 0; i < 44; ++i) {
        if (i < bc) {
            const float s = lg[i];
            uint4 vv = *(const uint4*)(vbase + (size_t)i * 64);
            acc[0] += s * bf2f_lo(vv.x); acc[1] += s * bf2f_hi(vv.x);
            acc[2] += s * bf2f_lo(vv.y); acc[3] += s * bf2f_hi(vv.y);
            acc[4] += s * bf2f_lo(vv.z); acc[5] += s * bf2f_hi(vv.z);
            acc[6] += s * bf2f_lo(vv.w); acc[7] += s * bf2f_hi(vv.w);
        }
    }

    const int b = bh >> 4;
    const int h = bh & 15;
    const float* sp = sall + bh * 64 + p * 8;
    float4 s0 = ((const float4*)sp)[0], s1 = ((const float4*)sp)[1];
    float o[8];
    o[0] = acc[0] + pm * s0.x; o[1] = acc[1] + pm * s0.y;
    o[2] = acc[2] + pm * s0.z; o[3] = acc[3] + pm * s0.w;
    o[4] = acc[4] + pm * s1.x; o[5] = acc[5] + pm * s1.y;
    o[6] = acc[6] + pm * s1.z; o[7] = acc[7] + pm * s1.w;

    unsigned u[4];
#pragma unroll
    for (int j = 0; j < 4; ++j)
        u[j] = (unsigned)f2bf_rne(o[2 * j]) | ((unsigned)f2bf_rne(o[2 * j + 1]) << 16);
    uint4* dstv = (uint4*)(outp + (((size_t)b * N + n) * 1024) + h * 64 + p * 8);
    dstv[0] = make_uint4(u[0], u[1], u[2], u[3]);
}

extern "C" void kernel_launch(void* const* d_in, const int* in_sizes, int n_in,
                              void* d_out, int out_size, void* d_ws, size_t ws_size,
                              hipStream_t stream)
{
    const float* x      = (const float*)d_in[0];
    const float* qkv_w  = (const float*)d_in[1];
    const float* proj_w = (const float*)d_in[2];
    const float* proj_b = (const float*)d_in[3];
    const int*   epoch  = (const int*)d_in[4];
    float* out = (float*)d_out;

    const size_t BHND = (size_t)2 * 16 * 2048 * 64;   // 4,194,304
    const size_t XN = 4194304, WN = 3145728;

    float*  qw   = (float*)d_ws;          // q fp32
    float*  kw   = qw + BHND;             // k fp32
    float*  sall = kw + BHND;             // 2048 used
    ushort* vw16 = (ushort*)(sall + 4096);// v bf16
    ushort* xh   = vw16 + BHND;
    ushort* xl   = xh + XN;
    ushort* wh   = xl + XN;
    ushort* wl   = wh + WN;
    ushort* pwh  = wl + WN;
    ushort* ao   = xh;   // alias: xh/xl dead after qkv gemms

    split_all<<<dim3(8192), dim3(256), 0, stream>>>(
        x, qkv_w, proj_w, xh, xl, wh, wl, pwh);

    // q,k columns (first 2048 of qkv_w rows): 3-term split, fp32 out
    gemm_mfma<3, 0><<<dim3(16, 32), dim3(256), 0, stream>>>(
        xh, xl, wh, wl, nullptr, qw, nullptr, 1024, 3072);

    // v columns (rows 2048..3071 of qkv_w): 1-term, bf16 out
    gemm_mfma<1, 2><<<dim3(8, 32), dim3(256), 0, stream>>>(
        xh, nullptr, wh + (size_t)2048 * 1024, nullptr, nullptr,
        nullptr, vw16, 1024, 3072);

    sall_sum<<<dim3(32), dim3(256), 0, stream>>>(vw16, sall);

    attn_band<<<dim3(2048), dim3(256), 0, stream>>>(qw, kw, vw16, sall, ao, epoch);

    gemm_mfma<1, 1><<<dim3(8, 32), dim3(256), 0, stream>>>(
        ao, nullptr, pwh, nullptr, proj_b, out, nullptr, 1024, 1024);
}

// Round 7
// 235.742 us; speedup vs baseline: 1.3654x; 1.1718x over previous
//
#include <hip/hip_runtime.h>
#include <cstddef>

// ---------------------------------------------------------------------------
// B=2, N=2048, C=1024, H=16, Dh=64, scale = Dh//H = 4
// qkv <3,0>: bf16x3 split MFMA -> q,k emitted as bf16 hi+lo pairs [B,H,N,64]
// qkv <1,2>: bf16 MFMA -> v bf16 [B,H,N,64]
// attn: MFMA flash-band. S = QK^T (3-term split), exact full-row softmax with
//       masked-logit (=1e-9) fold, P bf16 -> PV MFMA vs LDS-transposed V band.
// proj <1,1>: bf16 MFMA + bias -> fp32 out
// ---------------------------------------------------------------------------

typedef short  bf16x8 __attribute__((ext_vector_type(8)));
typedef float  f32x4  __attribute__((ext_vector_type(4)));

#define MFMA(a, b, c) __builtin_amdgcn_mfma_f32_16x16x32_bf16((a), (b), (c), 0, 0, 0)

__device__ __forceinline__ void gl_lds16(const void* g, void* l) {
    __builtin_amdgcn_global_load_lds(
        (const __attribute__((address_space(1))) void*)g,
        (__attribute__((address_space(3))) void*)l, 16, 0, 0);
}

__device__ __forceinline__ ushort f2bf_rne(float f) {
    unsigned b = __float_as_uint(f);
    b += 0x7FFFu + ((b >> 16) & 1u);
    return (ushort)(b >> 16);
}
__device__ __forceinline__ float bf2f_lo(unsigned u) { return __uint_as_float(u << 16); }

// ---------------------------------------------------------------------------
// fused fp32 -> bf16 split for all three tensors in one launch.
// ---------------------------------------------------------------------------
__global__ void split_all(const float* __restrict__ x,
                          const float* __restrict__ qkvw,
                          const float* __restrict__ projw,
                          ushort* __restrict__ xh, ushort* __restrict__ xl,
                          ushort* __restrict__ wh, ushort* __restrict__ wl,
                          ushort* __restrict__ pwh)
{
    const int i = blockIdx.x * 256 + threadIdx.x;
    const float* src; ushort* hi; ushort* lo; int j;
    if (i < 1048576)      { src = x;     hi = xh;  lo = xl;     j = i; }
    else if (i < 1835008) { src = qkvw;  hi = wh;  lo = wl;     j = i - 1048576; }
    else                  { src = projw; hi = pwh; lo = nullptr; j = i - 1835008; }

    float4 v = ((const float4*)src)[j];
    ushort h0 = f2bf_rne(v.x), h1 = f2bf_rne(v.y), h2 = f2bf_rne(v.z), h3 = f2bf_rne(v.w);
    ((ushort4*)hi)[j] = make_ushort4(h0, h1, h2, h3);
    if (lo) {
        float r0 = v.x - __uint_as_float((unsigned)h0 << 16);
        float r1 = v.y - __uint_as_float((unsigned)h1 << 16);
        float r2 = v.z - __uint_as_float((unsigned)h2 << 16);
        float r3 = v.w - __uint_as_float((unsigned)h3 << 16);
        ((ushort4*)lo)[j] = make_ushort4(f2bf_rne(r0), f2bf_rne(r1), f2bf_rne(r2), f2bf_rne(r3));
    }
}

// ---------------------------------------------------------------------------
// MFMA GEMM (m97 structure): 128x128 tile, BK=32, 4 waves x (4x4) 16x16x32.
// NTERMS=3: acc += Ah*Wh + Ah*Wl + Al*Wh.
// EPI=0: q,k -> bf16 hi/lo pairs: o16a=qh o16b=ql o16c=kh o16d=kl (n0<2048)
// EPI=1: out = acc + bias, fp32 row-major
// EPI=2: scatter bf16 into v [B,H,N,64] via o16a (W pre-offset to v cols)
// ---------------------------------------------------------------------------
template <int NTERMS, int EPI>
__global__ __launch_bounds__(256) void gemm_mfma(
    const ushort* __restrict__ Ah_g, const ushort* __restrict__ Al_g,
    const ushort* __restrict__ Wh_g, const ushort* __restrict__ Wl_g,
    const float* __restrict__ bias,
    float* __restrict__ out,
    ushort* __restrict__ o16a, ushort* __restrict__ o16b,
    ushort* __restrict__ o16c, ushort* __restrict__ o16d,
    int K, int Nout)
{
    __shared__ ushort smem[(NTERMS == 3 ? 4 : 2) * 4096];
    ushort* AhS = smem;
    ushort* AlS = (NTERMS == 3) ? smem + 4096 : nullptr;
    ushort* WhS = (NTERMS == 3) ? smem + 8192 : smem + 4096;
    ushort* WlS = (NTERMS == 3) ? smem + 12288 : nullptr;

    const int tid  = threadIdx.x;
    const int wid  = tid >> 6;
    const int lane = tid & 63;
    const int quad = lane >> 4;
    const int cl   = lane & 15;
    const int m0 = blockIdx.y * 128;
    const int n0 = blockIdx.x * 128;
    const int wm = (wid & 1) * 64;
    const int wn = (wid >> 1) * 64;

    const int srow = lane >> 2;
    const int scol = (lane & 3) * 8;

    const ushort* src; ushort* dst; int r0, c0;
    if (NTERMS == 3) {
        src = (wid == 0) ? Ah_g : (wid == 1) ? Al_g : (wid == 2) ? Wh_g : Wl_g;
        dst = (wid == 0) ? AhS : (wid == 1) ? AlS : (wid == 2) ? WhS : WlS;
        r0 = (wid < 2) ? m0 : n0;
        c0 = 0;
    } else {
        src = (wid < 2) ? Ah_g : Wh_g;
        dst = (wid < 2) ? AhS : WhS;
        r0 = (wid < 2) ? m0 : n0;
        c0 = (wid & 1) * 4;
    }

    f32x4 acc[4][4];
#pragma unroll
    for (int i = 0; i < 4; ++i)
#pragma unroll
        for (int j = 0; j < 4; ++j) acc[i][j] = (f32x4){0.f, 0.f, 0.f, 0.f};

    for (int k0 = 0; k0 < K; k0 += 32) {
#pragma unroll
        for (int c = 0; c < ((NTERMS == 3) ? 8 : 4); ++c) {
            const int cc = c0 + c;
            const ushort* g = src + (size_t)(r0 + cc * 16 + srow) * K + k0 + scol;
            gl_lds16(g, dst + cc * 512);
        }
        __syncthreads();

        bf16x8 ah[4], wh[4];
#pragma unroll
        for (int i = 0; i < 4; ++i) {
            ah[i] = ((const bf16x8*)AhS)[(wm + i * 16 + cl) * 4 + quad];
            wh[i] = ((const bf16x8*)WhS)[(wn + i * 16 + cl) * 4 + quad];
        }
        if (NTERMS == 3) {
            bf16x8 al[4], wl[4];
#pragma unroll
            for (int i = 0; i < 4; ++i) {
                al[i] = ((const bf16x8*)AlS)[(wm + i * 16 + cl) * 4 + quad];
                wl[i] = ((const bf16x8*)WlS)[(wn + i * 16 + cl) * 4 + quad];
            }
#pragma unroll
            for (int mi = 0; mi < 4; ++mi)
#pragma unroll
                for (int ni = 0; ni < 4; ++ni) {
                    acc[mi][ni] = MFMA(ah[mi], wh[ni], acc[mi][ni]);
                    acc[mi][ni] = MFMA(ah[mi], wl[ni], acc[mi][ni]);
                    acc[mi][ni] = MFMA(al[mi], wh[ni], acc[mi][ni]);
                }
        } else {
#pragma unroll
            for (int mi = 0; mi < 4; ++mi)
#pragma unroll
                for (int ni = 0; ni < 4; ++ni)
                    acc[mi][ni] = MFMA(ah[mi], wh[ni], acc[mi][ni]);
        }
        __syncthreads();
    }

    if (EPI == 1) {
        float bb[4];
#pragma unroll
        for (int ni = 0; ni < 4; ++ni) bb[ni] = bias[n0 + wn + ni * 16 + cl];
#pragma unroll
        for (int mi = 0; mi < 4; ++mi)
#pragma unroll
            for (int r = 0; r < 4; ++r) {
                const int gm = m0 + wm + mi * 16 + quad * 4 + r;
                float* rowp = out + (size_t)gm * Nout;
#pragma unroll
                for (int ni = 0; ni < 4; ++ni) {
                    const int gn = n0 + wn + ni * 16 + cl;
                    rowp[gn] = acc[mi][ni][r] + bb[ni];
                }
            }
    } else {
#pragma unroll
        for (int mi = 0; mi < 4; ++mi)
#pragma unroll
            for (int r = 0; r < 4; ++r) {
                const int gm = m0 + wm + mi * 16 + quad * 4 + r;
                const int b  = gm >> 11;
                const int nn = gm & 2047;
#pragma unroll
                for (int ni = 0; ni < 4; ++ni) {
                    const int gn = n0 + wn + ni * 16 + cl;
                    const int h  = (gn >> 6) & 15;
                    const int dh = gn & 63;
                    const size_t idx = (((size_t)b * 16 + h) * 2048 + nn) * 64 + dh;
                    const float v = acc[mi][ni][r];
                    if (EPI == 0) {
                        const int s = gn >> 10;       // 0:q 1:k (block-uniform)
                        const ushort hb = f2bf_rne(v);
                        const ushort lb = f2bf_rne(v - __uint_as_float((unsigned)hb << 16));
                        (s ? o16c : o16a)[idx] = hb;
                        (s ? o16d : o16b)[idx] = lb;
                    } else {                          // EPI == 2: v bf16
                        o16a[idx] = f2bf_rne(v);
                    }
                }
            }
    }
}

// S_all[bh][d] = sum_n v[bh][n][d] from bf16 v. 32 blocks x 256 thr, LDS reduce.
__global__ void sall_sum(const ushort* __restrict__ vg16, float* __restrict__ sall)
{
    __shared__ float red[4][64];
    const int bh = blockIdx.x;
    const int tid = threadIdx.x;
    const int d = tid & 63;
    const int c = tid >> 6;
    const ushort* base = vg16 + (((size_t)bh * 2048) + (size_t)c * 512) * 64 + d;
    float s = 0.f;
#pragma unroll 8
    for (int nn = 0; nn < 512; ++nn)
        s += bf2f_lo((unsigned)base[(size_t)nn * 64]);
    red[c][d] = s;
    __syncthreads();
    if (tid < 64)
        sall[bh * 64 + tid] = red[0][tid] + red[1][tid] + red[2][tid] + red[3][tid];
}

// ---------------------------------------------------------------------------
// MFMA flash-band attention. Block = one (b,h) x 64 q-rows, 4 waves, each wave
// owns 16 rows. S(16x112) = Q K^T via 3-term split MFMA (q,k as bf16 hi/lo).
// Softmax in C-layout regs (butterfly over the 16-lane cl group). P~ bf16 via
// same-wave LDS -> A-layout; PV vs LDS-transposed V band; + p_mask*S_all fold.
// ---------------------------------------------------------------------------
__global__ __launch_bounds__(256) void attn_mfma(
    const ushort* __restrict__ qh, const ushort* __restrict__ ql,
    const ushort* __restrict__ kh, const ushort* __restrict__ kl,
    const ushort* __restrict__ vg,
    const float* __restrict__ sall,
    ushort* __restrict__ outp,
    const int* __restrict__ epoch_ptr)
{
    const int N = 2048;
    const int w = (epoch_ptr[0] < 15) ? 16 : 20;

    __shared__ ushort Pl[4][16][144];   // per-wave P~ tile, rows 288B (4-way ok)
    __shared__ ushort VT[64][144];      // transposed V band [dim][seq]

    const int tid  = threadIdx.x;
    const int wid  = tid >> 6;
    const int lane = tid & 63;
    const int quad = lane >> 4;
    const int cl   = lane & 15;

    const int bh = blockIdx.x >> 5;
    const int n0 = (blockIdx.x & 31) << 6;
    const int lo = max(0, n0 - w);
    const int wm = wid * 16;
    const int hi = min(N - 1, n0 + 63 + w);
    const int cnt = hi - lo + 1;        // <= 104

    // zero VT (pad cols >= cnt stay zero; garbage would NaN-poison 0*x)
    for (int t = tid; t < 64 * 144 / 2; t += 256)
        ((unsigned*)VT)[t] = 0u;
    __syncthreads();

    // scatter V band (global, coalesced reads) into VT transposed
    for (int t = tid; t < 104 * 8; t += 256) {
        const int s  = t >> 3;
        const int db = (t & 7) * 8;
        if (s < cnt) {
            uint4 vv = *(const uint4*)(vg + (((size_t)bh * N) + lo + s) * 64 + db);
            VT[db + 0][s] = (ushort)(vv.x & 0xffff); VT[db + 1][s] = (ushort)(vv.x >> 16);
            VT[db + 2][s] = (ushort)(vv.y & 0xffff); VT[db + 3][s] = (ushort)(vv.y >> 16);
            VT[db + 4][s] = (ushort)(vv.z & 0xffff); VT[db + 5][s] = (ushort)(vv.z >> 16);
            VT[db + 6][s] = (ushort)(vv.w & 0xffff); VT[db + 7][s] = (ushort)(vv.w >> 16);
        }
    }
    // (no barrier yet: S/softmax below overlaps the scatter; barrier before PV)

    // Q A-frags straight from global (lane cl = row, quad = k-offset)
    const ushort* qhp = qh + ((size_t)bh * N + n0 + wm + cl) * 64;
    const ushort* qlp = ql + ((size_t)bh * N + n0 + wm + cl) * 64;
    const bf16x8 aqh0 = *(const bf16x8*)(qhp + quad * 8);
    const bf16x8 aqh1 = *(const bf16x8*)(qhp + 32 + quad * 8);
    const bf16x8 aql0 = *(const bf16x8*)(qlp + quad * 8);
    const bf16x8 aql1 = *(const bf16x8*)(qlp + 32 + quad * 8);

    // S tiles: 7 ni x (K=64 in 2 steps) x 3 terms
    f32x4 sacc[7];
#pragma unroll
    for (int ni = 0; ni < 7; ++ni) {
        int krow = lo + ni * 16 + cl;
        krow = min(krow, N - 1);                 // clamped rows are masked later
        const ushort* khp = kh + ((size_t)bh * N + krow) * 64;
        const ushort* klp = kl + ((size_t)bh * N + krow) * 64;
        const bf16x8 bh0 = *(const bf16x8*)(khp + quad * 8);
        const bf16x8 bh1 = *(const bf16x8*)(khp + 32 + quad * 8);
        const bf16x8 bl0 = *(const bf16x8*)(klp + quad * 8);
        const bf16x8 bl1 = *(const bf16x8*)(klp + 32 + quad * 8);
        f32x4 s = (f32x4){0.f, 0.f, 0.f, 0.f};
        s = MFMA(aqh0, bh0, s); s = MFMA(aqh1, bh1, s);
        s = MFMA(aqh0, bl0, s); s = MFMA(aqh1, bl1, s);
        s = MFMA(aql0, bh0, s); s = MFMA(aql1, bh1, s);
        sacc[ni] = s;
    }

    // softmax per row r (C-layout: row = quad*4+r, col = ni*16+cl)
    float pm[4];
#pragma unroll
    for (int r = 0; r < 4; ++r) {
        const int n = n0 + wm + quad * 4 + r;
        const int jlo = max(0, n - w), jhi = min(N - 1, n + w);
        const int bc = jhi - jlo + 1;
        float mx = 1e-9f;
#pragma unroll
        for (int ni = 0; ni < 7; ++ni) {
            const int j = lo + ni * 16 + cl;
            const bool val = (j >= n - w) && (j <= n + w) && (j < N);
            const float sv = 4.0f * sacc[ni][r];
            if (val) mx = fmaxf(mx, sv);
        }
        mx = fmaxf(mx, __shfl_xor(mx, 1));
        mx = fmaxf(mx, __shfl_xor(mx, 2));
        mx = fmaxf(mx, __shfl_xor(mx, 4));
        mx = fmaxf(mx, __shfl_xor(mx, 8));
        const float em = __expf(1e-9f - mx);
        float e[7];
        float sum = 0.f;
#pragma unroll
        for (int ni = 0; ni < 7; ++ni) {
            const int j = lo + ni * 16 + cl;
            const bool val = (j >= n - w) && (j <= n + w) && (j < N);
            const float ev = val ? __expf(4.0f * sacc[ni][r] - mx) : 0.f;
            e[ni] = val ? (ev - em) : 0.f;
            sum += ev;
        }
        sum += __shfl_xor(sum, 1);
        sum += __shfl_xor(sum, 2);
        sum += __shfl_xor(sum, 4);
        sum += __shfl_xor(sum, 8);
        const float inv = 1.0f / ((float)(N - bc) * em + sum);
        pm[r] = em * inv;
#pragma unroll
        for (int ni = 0; ni < 7; ++ni)
            sacc[ni][r] = e[ni] * inv;           // P~ = (e - em)/denom
    }

    // P~ -> LDS bf16 (same-wave slice) + zero the k-pad cols 112..143
#pragma unroll
    for (int ni = 0; ni < 7; ++ni)
#pragma unroll
        for (int r = 0; r < 4; ++r)
            Pl[wid][quad * 4 + r][ni * 16 + cl] = f2bf_rne(sacc[ni][r]);
    {
        const int prow = lane >> 2;
        const int pc = 112 + (lane & 3) * 8;
        *(uint4*)&Pl[wid][prow][pc] = make_uint4(0u, 0u, 0u, 0u);
    }

    __syncthreads();   // VT scatter complete (and P~ safely ordered)

    // PV: out(16 rows x 64 dims) = P~ (16x128) . Vband (128x64)
    const int b = bh >> 4, h = bh & 15;
#pragma unroll
    for (int dn = 0; dn < 4; ++dn) {
        f32x4 o = (f32x4){0.f, 0.f, 0.f, 0.f};
#pragma unroll
        for (int k0 = 0; k0 < 128; k0 += 32) {
            const bf16x8 a  = *(const bf16x8*)&Pl[wid][cl][k0 + quad * 8];
            const bf16x8 bb = *(const bf16x8*)&VT[dn * 16 + cl][k0 + quad * 8];
            o = MFMA(a, bb, o);
        }
        const int d = dn * 16 + cl;
        const float sv = sall[bh * 64 + d];
#pragma unroll
        for (int r = 0; r < 4; ++r) {
            const int n = n0 + wm + quad * 4 + r;
            outp[((size_t)b * N + n) * 1024 + h * 64 + d] = f2bf_rne(o[r] + pm[r] * sv);
        }
    }
}

extern "C" void kernel_launch(void* const* d_in, const int* in_sizes, int n_in,
                              void* d_out, int out_size, void* d_ws, size_t ws_size,
                              hipStream_t stream)
{
    const float* x      = (const float*)d_in[0];
    const float* qkv_w  = (const float*)d_in[1];
    const float* proj_w = (const float*)d_in[2];
    const float* proj_b = (const float*)d_in[3];
    const int*   epoch  = (const int*)d_in[4];
    float* out = (float*)d_out;

    const size_t BHND = (size_t)2 * 16 * 2048 * 64;   // 4,194,304
    const size_t XN = 4194304, WN = 3145728;

    ushort* qhw  = (ushort*)d_ws;
    ushort* qlw  = qhw + BHND;
    ushort* khw  = qlw + BHND;
    ushort* klw  = khw + BHND;
    ushort* vw16 = klw + BHND;
    float*  sall = (float*)(vw16 + BHND);     // 2048 floats
    ushort* xh   = (ushort*)(sall + 4096);
    ushort* xl   = xh + XN;
    ushort* wh   = xl + XN;
    ushort* wl   = wh + WN;
    ushort* pwh  = wl + WN;
    ushort* ao   = xh;   // alias: xh/xl dead after qkv gemms

    split_all<<<dim3(8192), dim3(256), 0, stream>>>(
        x, qkv_w, proj_w, xh, xl, wh, wl, pwh);

    // q,k columns: 3-term split -> bf16 hi/lo pairs
    gemm_mfma<3, 0><<<dim3(16, 32), dim3(256), 0, stream>>>(
        xh, xl, wh, wl, nullptr, nullptr,
        qhw, qlw, khw, klw, 1024, 3072);

    // v columns: 1-term -> bf16
    gemm_mfma<1, 2><<<dim3(8, 32), dim3(256), 0, stream>>>(
        xh, nullptr, wh + (size_t)2048 * 1024, nullptr, nullptr, nullptr,
        vw16, nullptr, nullptr, nullptr, 1024, 3072);

    sall_sum<<<dim3(32), dim3(256), 0, stream>>>(vw16, sall);

    attn_mfma<<<dim3(1024), dim3(256), 0, stream>>>(
        qhw, qlw, khw, klw, vw16, sall, ao, epoch);

    gemm_mfma<1, 1><<<dim3(8, 32), dim3(256), 0, stream>>>(
        ao, nullptr, pwh, nullptr, proj_b, out,
        nullptr, nullptr, nullptr, nullptr, 1024, 1024);
}

// Round 8
// 185.540 us; speedup vs baseline: 1.7349x; 1.2706x over previous
//
#include <hip/hip_runtime.h>
#include <cstddef>

// ---------------------------------------------------------------------------
// B=2, N=2048, C=1024, H=16, Dh=64, scale = Dh//H = 4
// ALL-FP16 pipeline (fp16 = 11 mantissa bits; replaces round-7's bf16x3 split):
//   split_all: x, qkv_w, proj_w -> fp16
//   gemm_mfma<0>: one uniform launch -> q|k|v fp16 [B,H,N,64]
//   attn_mfma: S = QK^T fp16 MFMA, exact full-row softmax with masked-logit
//              (=1e-9) fold, P fp16 -> PV MFMA vs LDS-transposed V band.
//   gemm_mfma<1>: proj fp16 MFMA + bias -> fp32 out
// ---------------------------------------------------------------------------

typedef _Float16 f16x8 __attribute__((ext_vector_type(8)));
typedef float    f32x4 __attribute__((ext_vector_type(4)));

#define MFMA16(a, b, c) __builtin_amdgcn_mfma_f32_16x16x32_f16((a), (b), (c), 0, 0, 0)

__device__ __forceinline__ void gl_lds16(const void* g, void* l) {
    __builtin_amdgcn_global_load_lds(
        (const __attribute__((address_space(1))) void*)g,
        (__attribute__((address_space(3))) void*)l, 16, 0, 0);
}

__device__ __forceinline__ ushort f2h(float f) {
    _Float16 h = (_Float16)f;
    return *(ushort*)&h;
}
__device__ __forceinline__ float h2f(ushort u) {
    _Float16 h = *(_Float16*)&u;
    return (float)h;
}

// ---------------------------------------------------------------------------
// fused fp32 -> fp16 conversion for all three tensors in one launch.
// x: 1048576 float4, qkv_w: 786432, proj_w: 262144
// ---------------------------------------------------------------------------
__global__ void split_all(const float* __restrict__ x,
                          const float* __restrict__ qkvw,
                          const float* __restrict__ projw,
                          ushort* __restrict__ x16,
                          ushort* __restrict__ w16,
                          ushort* __restrict__ pw16)
{
    const int i = blockIdx.x * 256 + threadIdx.x;
    const float* src; ushort* dst; int j;
    if (i < 1048576)      { src = x;     dst = x16;  j = i; }
    else if (i < 1835008) { src = qkvw;  dst = w16;  j = i - 1048576; }
    else                  { src = projw; dst = pw16; j = i - 1835008; }

    float4 v = ((const float4*)src)[j];
    ((ushort4*)dst)[j] = make_ushort4(f2h(v.x), f2h(v.y), f2h(v.z), f2h(v.w));
}

// ---------------------------------------------------------------------------
// MFMA GEMM (m97 structure): 128x128 tile, BK=32, 4 waves x (4x4) 16x16x32 f16.
// EPI=0: scatter fp16 into q|k|v [3][B,H,N,64] (out16 = qkv base)
// EPI=1: out = acc + bias, fp32 row-major
// ---------------------------------------------------------------------------
template <int EPI>
__global__ __launch_bounds__(256) void gemm_mfma(
    const ushort* __restrict__ A_g, const ushort* __restrict__ W_g,
    const float* __restrict__ bias,
    float* __restrict__ out, ushort* __restrict__ out16,
    int K, int Nout)
{
    __shared__ ushort smem[8192];
    ushort* AS = smem;
    ushort* WS = smem + 4096;

    const int tid  = threadIdx.x;
    const int wid  = tid >> 6;
    const int lane = tid & 63;
    const int quad = lane >> 4;
    const int cl   = lane & 15;
    const int m0 = blockIdx.y * 128;
    const int n0 = blockIdx.x * 128;
    const int wm = (wid & 1) * 64;
    const int wn = (wid >> 1) * 64;

    const int srow = lane >> 2;
    const int scol = (lane & 3) * 8;

    const ushort* src = (wid < 2) ? A_g : W_g;
    ushort* dst = (wid < 2) ? AS : WS;
    const int r0 = (wid < 2) ? m0 : n0;
    const int c0 = (wid & 1) * 4;

    f32x4 acc[4][4];
#pragma unroll
    for (int i = 0; i < 4; ++i)
#pragma unroll
        for (int j = 0; j < 4; ++j) acc[i][j] = (f32x4){0.f, 0.f, 0.f, 0.f};

    for (int k0 = 0; k0 < K; k0 += 32) {
#pragma unroll
        for (int c = 0; c < 4; ++c) {
            const int cc = c0 + c;
            gl_lds16(src + (size_t)(r0 + cc * 16 + srow) * K + k0 + scol, dst + cc * 512);
        }
        __syncthreads();

        f16x8 ah[4], wh[4];
#pragma unroll
        for (int i = 0; i < 4; ++i) {
            ah[i] = ((const f16x8*)AS)[(wm + i * 16 + cl) * 4 + quad];
            wh[i] = ((const f16x8*)WS)[(wn + i * 16 + cl) * 4 + quad];
        }
#pragma unroll
        for (int mi = 0; mi < 4; ++mi)
#pragma unroll
            for (int ni = 0; ni < 4; ++ni)
                acc[mi][ni] = MFMA16(ah[mi], wh[ni], acc[mi][ni]);
        __syncthreads();
    }

    if (EPI == 1) {
        float bb[4];
#pragma unroll
        for (int ni = 0; ni < 4; ++ni) bb[ni] = bias[n0 + wn + ni * 16 + cl];
#pragma unroll
        for (int mi = 0; mi < 4; ++mi)
#pragma unroll
            for (int r = 0; r < 4; ++r) {
                const int gm = m0 + wm + mi * 16 + quad * 4 + r;
                float* rowp = out + (size_t)gm * Nout;
#pragma unroll
                for (int ni = 0; ni < 4; ++ni) {
                    const int gn = n0 + wn + ni * 16 + cl;
                    rowp[gn] = acc[mi][ni][r] + bb[ni];
                }
            }
    } else {
#pragma unroll
        for (int mi = 0; mi < 4; ++mi)
#pragma unroll
            for (int r = 0; r < 4; ++r) {
                const int gm = m0 + wm + mi * 16 + quad * 4 + r;
                const int b  = gm >> 11;
                const int nn = gm & 2047;
#pragma unroll
                for (int ni = 0; ni < 4; ++ni) {
                    const int gn = n0 + wn + ni * 16 + cl;
                    const int s  = gn >> 10;          // 0:q 1:k 2:v
                    const int h  = (gn >> 6) & 15;
                    const int dh = gn & 63;
                    out16[(size_t)s * 4194304u + (((size_t)b * 16 + h) * 2048 + nn) * 64 + dh]
                        = f2h(acc[mi][ni][r]);
                }
            }
    }
}

// S_all[bh][d] = sum_n v[bh][n][d] from fp16 v. 32 blocks x 256 thr, LDS reduce.
__global__ void sall_sum(const ushort* __restrict__ vg16, float* __restrict__ sall)
{
    __shared__ float red[4][64];
    const int bh = blockIdx.x;
    const int tid = threadIdx.x;
    const int d = tid & 63;
    const int c = tid >> 6;
    const ushort* base = vg16 + (((size_t)bh * 2048) + (size_t)c * 512) * 64 + d;
    float s = 0.f;
#pragma unroll 8
    for (int nn = 0; nn < 512; ++nn)
        s += h2f(base[(size_t)nn * 64]);
    red[c][d] = s;
    __syncthreads();
    if (tid < 64)
        sall[bh * 64 + tid] = red[0][tid] + red[1][tid] + red[2][tid] + red[3][tid];
}

// ---------------------------------------------------------------------------
// MFMA flash-band attention (fp16). Block = one (b,h) x 64 q-rows, 4 waves,
// each wave owns 16 rows. S(16x112) = Q K^T fp16 MFMA. Softmax in C-layout
// regs (butterfly over 16-lane cl group). P~ fp16 via same-wave LDS ->
// A-layout; PV vs LDS-transposed V band; + p_mask*S_all fold.
// ---------------------------------------------------------------------------
__global__ __launch_bounds__(256) void attn_mfma(
    const ushort* __restrict__ qg, const ushort* __restrict__ kg,
    const ushort* __restrict__ vg,
    const float* __restrict__ sall,
    ushort* __restrict__ outp,
    const int* __restrict__ epoch_ptr)
{
    const int N = 2048;
    const int w = (epoch_ptr[0] < 15) ? 16 : 20;

    __shared__ ushort Pl[4][16][144];   // per-wave P~ tile
    __shared__ ushort VT[64][144];      // transposed V band [dim][seq]

    const int tid  = threadIdx.x;
    const int wid  = tid >> 6;
    const int lane = tid & 63;
    const int quad = lane >> 4;
    const int cl   = lane & 15;

    const int bh = blockIdx.x >> 5;
    const int n0 = (blockIdx.x & 31) << 6;
    const int lo = max(0, n0 - w);
    const int wm = wid * 16;
    const int hi = min(N - 1, n0 + 63 + w);
    const int cnt = hi - lo + 1;        // <= 104

    // zero VT (pad cols >= cnt stay zero)
    for (int t = tid; t < 64 * 144 / 2; t += 256)
        ((unsigned*)VT)[t] = 0u;
    __syncthreads();

    // scatter V band (coalesced reads) into VT transposed
    for (int t = tid; t < 104 * 8; t += 256) {
        const int s  = t >> 3;
        const int db = (t & 7) * 8;
        if (s < cnt) {
            uint4 vv = *(const uint4*)(vg + (((size_t)bh * N) + lo + s) * 64 + db);
            VT[db + 0][s] = (ushort)(vv.x & 0xffff); VT[db + 1][s] = (ushort)(vv.x >> 16);
            VT[db + 2][s] = (ushort)(vv.y & 0xffff); VT[db + 3][s] = (ushort)(vv.y >> 16);
            VT[db + 4][s] = (ushort)(vv.z & 0xffff); VT[db + 5][s] = (ushort)(vv.z >> 16);
            VT[db + 6][s] = (ushort)(vv.w & 0xffff); VT[db + 7][s] = (ushort)(vv.w >> 16);
        }
    }
    // (no barrier yet: S/softmax below overlaps the scatter; barrier before PV)

    // Q A-frags straight from global (lane cl = row, quad = k-offset)
    const ushort* qp = qg + ((size_t)bh * N + n0 + wm + cl) * 64;
    const f16x8 aq0 = *(const f16x8*)(qp + quad * 8);
    const f16x8 aq1 = *(const f16x8*)(qp + 32 + quad * 8);

    // S tiles: 7 ni x (K=64 in 2 steps)
    f32x4 sacc[7];
#pragma unroll
    for (int ni = 0; ni < 7; ++ni) {
        int krow = lo + ni * 16 + cl;
        krow = min(krow, N - 1);                 // clamped rows masked later
        const ushort* kp = kg + ((size_t)bh * N + krow) * 64;
        const f16x8 bk0 = *(const f16x8*)(kp + quad * 8);
        const f16x8 bk1 = *(const f16x8*)(kp + 32 + quad * 8);
        f32x4 s = (f32x4){0.f, 0.f, 0.f, 0.f};
        s = MFMA16(aq0, bk0, s);
        s = MFMA16(aq1, bk1, s);
        sacc[ni] = s;
    }

    // softmax per row r (C-layout: row = quad*4+r, col = ni*16+cl)
    float pm[4];
#pragma unroll
    for (int r = 0; r < 4; ++r) {
        const int n = n0 + wm + quad * 4 + r;
        const int jlo = max(0, n - w), jhi = min(N - 1, n + w);
        const int bc = jhi - jlo + 1;
        float mx = 1e-9f;
#pragma unroll
        for (int ni = 0; ni < 7; ++ni) {
            const int j = lo + ni * 16 + cl;
            const bool val = (j >= n - w) && (j <= n + w) && (j < N);
            const float sv = 4.0f * sacc[ni][r];
            if (val) mx = fmaxf(mx, sv);
        }
        mx = fmaxf(mx, __shfl_xor(mx, 1));
        mx = fmaxf(mx, __shfl_xor(mx, 2));
        mx = fmaxf(mx, __shfl_xor(mx, 4));
        mx = fmaxf(mx, __shfl_xor(mx, 8));
        const float em = __expf(1e-9f - mx);
        float e[7];
        float sum = 0.f;
#pragma unroll
        for (int ni = 0; ni < 7; ++ni) {
            const int j = lo + ni * 16 + cl;
            const bool val = (j >= n - w) && (j <= n + w) && (j < N);
            const float ev = val ? __expf(4.0f * sacc[ni][r] - mx) : 0.f;
            e[ni] = val ? (ev - em) : 0.f;
            sum += ev;
        }
        sum += __shfl_xor(sum, 1);
        sum += __shfl_xor(sum, 2);
        sum += __shfl_xor(sum, 4);
        sum += __shfl_xor(sum, 8);
        const float inv = 1.0f / ((float)(N - bc) * em + sum);
        pm[r] = em * inv;
#pragma unroll
        for (int ni = 0; ni < 7; ++ni)
            sacc[ni][r] = e[ni] * inv;           // P~ = (e - em)/denom
    }

    // P~ -> LDS fp16 (same-wave slice) + zero the k-pad cols 112..143
#pragma unroll
    for (int ni = 0; ni < 7; ++ni)
#pragma unroll
        for (int r = 0; r < 4; ++r)
            Pl[wid][quad * 4 + r][ni * 16 + cl] = f2h(sacc[ni][r]);
    {
        const int prow = lane >> 2;
        const int pc = 112 + (lane & 3) * 8;
        *(uint4*)&Pl[wid][prow][pc] = make_uint4(0u, 0u, 0u, 0u);
    }

    __syncthreads();   // VT scatter complete (and P~ safely ordered)

    // PV: out(16 rows x 64 dims) = P~ (16x128) . Vband (128x64)
    const int b = bh >> 4, h = bh & 15;
#pragma unroll
    for (int dn = 0; dn < 4; ++dn) {
        f32x4 o = (f32x4){0.f, 0.f, 0.f, 0.f};
#pragma unroll
        for (int k0 = 0; k0 < 128; k0 += 32) {
            const f16x8 a  = *(const f16x8*)&Pl[wid][cl][k0 + quad * 8];
            const f16x8 bb = *(const f16x8*)&VT[dn * 16 + cl][k0 + quad * 8];
            o = MFMA16(a, bb, o);
        }
        const int d = dn * 16 + cl;
        const float sv = sall[bh * 64 + d];
#pragma unroll
        for (int r = 0; r < 4; ++r) {
            const int n = n0 + wm + quad * 4 + r;
            outp[((size_t)b * N + n) * 1024 + h * 64 + d] = f2h(o[r] + pm[r] * sv);
        }
    }
}

extern "C" void kernel_launch(void* const* d_in, const int* in_sizes, int n_in,
                              void* d_out, int out_size, void* d_ws, size_t ws_size,
                              hipStream_t stream)
{
    const float* x      = (const float*)d_in[0];
    const float* qkv_w  = (const float*)d_in[1];
    const float* proj_w = (const float*)d_in[2];
    const float* proj_b = (const float*)d_in[3];
    const int*   epoch  = (const int*)d_in[4];
    float* out = (float*)d_out;

    const size_t BHND = (size_t)2 * 16 * 2048 * 64;   // 4,194,304
    const size_t XN = 4194304, WN = 3145728;

    ushort* qkv16 = (ushort*)d_ws;            // q|k|v fp16, contiguous
    ushort* q16   = qkv16;
    ushort* k16   = qkv16 + BHND;
    ushort* v16   = qkv16 + 2 * BHND;
    float*  sall  = (float*)(qkv16 + 3 * BHND);   // 2048 floats (pad 4096)
    ushort* x16   = (ushort*)(sall + 4096);
    ushort* w16   = x16 + XN;
    ushort* pw16  = w16 + WN;
    ushort* ao    = x16;   // alias: x16 dead after qkv gemm

    split_all<<<dim3(8192), dim3(256), 0, stream>>>(x, qkv_w, proj_w, x16, w16, pw16);

    // qkv: one uniform fp16 launch, scatter q|k|v
    gemm_mfma<0><<<dim3(24, 32), dim3(256), 0, stream>>>(
        x16, w16, nullptr, nullptr, qkv16, 1024, 3072);

    sall_sum<<<dim3(32), dim3(256), 0, stream>>>(v16, sall);

    attn_mfma<<<dim3(1024), dim3(256), 0, stream>>>(
        q16, k16, v16, sall, ao, epoch);

    gemm_mfma<1><<<dim3(8, 32), dim3(256), 0, stream>>>(
        ao, pw16, proj_b, out, nullptr, 1024, 1024);
}